// Round 4
// baseline (213.713 us; speedup 1.0000x reference)
//
#include <hip/hip_runtime.h>
#include <math.h>

#define NT 256
#define MAXG 1536   // actual G ~= 1366; LDS: 1536*32 + 1536*4 = 55.3 KB -> 2 blocks/CU
#define DELTA 0.002f  // > 2*eps_f32(score) ~= 3.4e-4; conservative

typedef float v2f __attribute__((ext_vector_type(2)));

struct PassOut { double err; int idx; };

__global__ __launch_bounds__(NT, 2)
void e8p_quant_kernel(const float* __restrict__ X,
                      const float* __restrict__ grid_part,
                      const float* __restrict__ grid_norm,
                      const int* __restrict__ pam,
                      float* __restrict__ out,
                      int N, int G)
{
#pragma clang fp contract(off)
    __shared__ float lg[MAXG * 8];
    __shared__ float ln[MAXG];

    const float4* gp4 = reinterpret_cast<const float4*>(grid_part);
    float4* lg4w = reinterpret_cast<float4*>(lg);
    for (int j = threadIdx.x; j < G; j += NT) {
        lg4w[2 * j]     = gp4[2 * j];
        lg4w[2 * j + 1] = gp4[2 * j + 1];
        ln[j] = grid_norm[j];   // norms are multiples of 0.25 <= 12: exact in f32
    }
    __syncthreads();

    int r = blockIdx.x * NT + threadIdx.x;
    if (r >= N) return;

    const float4* x4 = reinterpret_cast<const float4*>(X);
    float4 a0 = x4[2 * r], a1 = x4[2 * r + 1];
    float xf[8] = {a0.x, a0.y, a0.z, a0.w, a1.x, a1.y, a1.z, a1.w};

    // f32 shifted/abs parts for the filter. Sign bits: x+-0.25 cancellation is
    // EXACT in f32 (both operands f32, near-cancel => Sterbenz), so the f32
    // sign test matches the f64 one bit-for-bit.
    float xpf[8], xmf[8];
    int nbp = 0, nbm = 0;
#pragma unroll
    for (int k = 0; k < 8; ++k) {
        float sp = xf[k] + 0.25f, sm = xf[k] - 0.25f;
        nbp |= int(sp < 0.0f) << k;
        nbm |= int(sm < 0.0f) << k;
        xpf[k] = fabsf(sp); xmf[k] = fabsf(sm);
    }
    int oddp = __popc(nbp) & 1, oddm = __popc(nbm) & 1;
    if (oddp) xpf[7] = -xpf[7];
    if (oddm) xmf[7] = -xmf[7];
    int msbp = nbp ^ (oddp << 7);
    int msbm = nbm ^ (oddm << 7);

    v2f xp01 = {xpf[0], xpf[1]}, xp23 = {xpf[2], xpf[3]};
    v2f xp45 = {xpf[4], xpf[5]}, xp67 = {xpf[6], xpf[7]};
    v2f xm01 = {xmf[0], xmf[1]}, xm23 = {xmf[2], xmf[3]};
    v2f xm45 = {xmf[4], xmf[5]}, xm67 = {xmf[6], xmf[7]};

    const float4* lg4 = reinterpret_cast<const float4*>(lg);

    // f32 prefilter state: running max + 4-slot candidate ring (oldest=slot3)
    // + max score ever evicted (soundness guard).
    float bestp = -3.0e38f, bestm = -3.0e38f;
    float evp = -3.0e38f, evm = -3.0e38f;
    float sp0 = -3.0e38f, sp1 = -3.0e38f, sp2 = -3.0e38f, sp3 = -3.0e38f;
    float sm0 = -3.0e38f, sm1 = -3.0e38f, sm2 = -3.0e38f, sm3 = -3.0e38f;
    int jp0 = 0, jp1 = 0, jp2 = 0, jp3 = 0;
    int jm0 = 0, jm1 = 0, jm2 = 0, jm3 = 0;

#pragma unroll 2
    for (int j = 0; j < G; ++j) {
        float4 ga = lg4[2 * j], gb = lg4[2 * j + 1];
        float nn = ln[j];
        v2f g01 = {ga.x, ga.y}, g23 = {ga.z, ga.w};
        v2f g45 = {gb.x, gb.y}, g67 = {gb.z, gb.w};

        v2f accp = xp01 * g01;                              // v_pk_mul_f32
        accp = __builtin_elementwise_fma(xp23, g23, accp);  // v_pk_fma_f32
        accp = __builtin_elementwise_fma(xp45, g45, accp);
        accp = __builtin_elementwise_fma(xp67, g67, accp);
        float sp = fmaf(2.0f, accp.x + accp.y, -nn);

        v2f accm = xm01 * g01;
        accm = __builtin_elementwise_fma(xm23, g23, accm);
        accm = __builtin_elementwise_fma(xm45, g45, accm);
        accm = __builtin_elementwise_fma(xm67, g67, accm);
        float sm = fmaf(2.0f, accm.x + accm.y, -nn);

        if (sp + DELTA > bestp) {   // rare (~7/1366 per lane): insert candidate
            evp = fmaxf(evp, sp3);
            sp3 = sp2; jp3 = jp2; sp2 = sp1; jp2 = jp1; sp1 = sp0; jp1 = jp0;
            sp0 = sp;  jp0 = j;
        }
        bestp = fmaxf(bestp, sp);
        if (sm + DELTA > bestm) {
            evm = fmaxf(evm, sm3);
            sm3 = sm2; jm3 = jm2; sm2 = sm1; jm2 = jm1; sm1 = sm0; jm1 = jm0;
            sm0 = sm;  jm0 = j;
        }
        bestm = fmaxf(bestm, sm);
    }

    // exact f64 parts (x +- 0.25 exact in f64), same as the R3-passing kernel
    double xpd[8], xmd[8];
#pragma unroll
    for (int k = 0; k < 8; ++k) {
        double xd = (double)xf[k];
        xpd[k] = fabs(xd + 0.25);
        xmd[k] = fabs(xd - 0.25);
    }
    if (oddp) xpd[7] = -xpd[7];
    if (oddm) xmd[7] = -xmd[7];

    // bit-identical exact score from R3: sequential fma chain + fma(2,d,-n)
    auto exactScore = [&](int j, const double* xd) -> double {
        float4 ga = lg4[2 * j], gb = lg4[2 * j + 1];
        double s = xd[0] * (double)ga.x;
        s = fma(xd[1], (double)ga.y, s);
        s = fma(xd[2], (double)ga.z, s);
        s = fma(xd[3], (double)ga.w, s);
        s = fma(xd[4], (double)gb.x, s);
        s = fma(xd[5], (double)gb.y, s);
        s = fma(xd[6], (double)gb.z, s);
        s = fma(xd[7], (double)gb.w, s);
        return fma(2.0, s, -(double)ln[j]);
    };

    // Resolve: exact-eval ring slots within the band, oldest->newest
    // (increasing j) with strict > == np.argmax first-max-wins.
    int ip = 0, im = 0;
    bool okp = evp < bestp - DELTA;   // no in-band candidate was evicted
    bool okm = evm < bestm - DELTA;
    if (okp) {
        double bd = -1.0e300; float thr = bestp - DELTA;
        if (sp3 >= thr) { double sd = exactScore(jp3, xpd); if (sd > bd) { bd = sd; ip = jp3; } }
        if (sp2 >= thr) { double sd = exactScore(jp2, xpd); if (sd > bd) { bd = sd; ip = jp2; } }
        if (sp1 >= thr) { double sd = exactScore(jp1, xpd); if (sd > bd) { bd = sd; ip = jp1; } }
        if (sp0 >= thr) { double sd = exactScore(jp0, xpd); if (sd > bd) { bd = sd; ip = jp0; } }
    }
    if (okm) {
        double bd = -1.0e300; float thr = bestm - DELTA;
        if (sm3 >= thr) { double sd = exactScore(jm3, xmd); if (sd > bd) { bd = sd; im = jm3; } }
        if (sm2 >= thr) { double sd = exactScore(jm2, xmd); if (sd > bd) { bd = sd; im = jm2; } }
        if (sm1 >= thr) { double sd = exactScore(jm1, xmd); if (sd > bd) { bd = sd; im = jm1; } }
        if (sm0 >= thr) { double sd = exactScore(jm0, xmd); if (sd > bd) { bd = sd; im = jm0; } }
    }
    if (!okp || !okm) {   // sound fallback: full exact scan (rare lanes)
        double bpd = -1.0e300, bmd = -1.0e300;
        int ipd = 0, imd = 0;
        for (int j = 0; j < G; ++j) {
            double s1 = exactScore(j, xpd);
            double s2 = exactScore(j, xmd);
            if (s1 > bpd) { bpd = s1; ipd = j; }
            if (s2 > bmd) { bmd = s2; imd = j; }
        }
        ip = ipd; im = imd;
    }

    auto finish = [&](int bi, double sgn_quarter, int msb, int par, double* v) -> PassOut {
#pragma clang fp contract(off)
        float4 ga = lg4[2 * bi], gb = lg4[2 * bi + 1];
        float g[8] = {ga.x, ga.y, ga.z, ga.w, gb.x, gb.y, gb.z, gb.w};
        int gneg = 0; float sumabs = 0.0f;
#pragma unroll
        for (int k = 0; k < 8; ++k) {
            gneg |= int(g[k] < 0.0f) << k;
            sumabs += fabsf(g[k]);
        }
        double vv[8];
#pragma unroll
        for (int k = 0; k < 8; ++k) {
            unsigned u = __float_as_uint(g[k]) ^ ((((unsigned)msb >> k) & 1u) << 31);
            double val = (double)__uint_as_float(u);
            vv[k] = val;
            v[k] = val;
        }
        double d[8];
#pragma unroll
        for (int k = 0; k < 8; ++k) {
            double xs = (double)xf[k] + sgn_quarter;
            d[k] = xs - vv[k];
        }
        double s0 = d[0]*d[0], s1 = d[1]*d[1], s2 = d[2]*d[2], s3 = d[3]*d[3];
        double s4 = d[4]*d[4], s5 = d[5]*d[5], s6 = d[6]*d[6], s7 = d[7]*d[7];
        double e = ((s0 + s1) + (s2 + s3)) + ((s4 + s5) + (s6 + s7));
        double err = sqrt(e);
        int godd = ((int)(sumabs + 0.5f)) & 1;
        int sb = gneg ^ msb;
        int mi = (((sb >> 0) & 1) ^ par)
               | (((sb >> 2) & 1) << 1)
               | (((sb >> 4) & 1) << 2)
               | (((sb >> 6) & 1) << 3)
               | (((sb >> 1) & 1) << 4)
               | (((sb >> 3) & 1) << 5)
               | (((sb >> 5) & 1) << 6)
               | ((((sb >> 7) & 1) ^ godd) << 7);
        PassOut po;
        po.err = err;
        po.idx = (pam[bi] << 8) + mi;
        return po;
    };

    double vp[8], vm[8];
    PassOut P = finish(ip, +0.25, msbp, 1, vp);
    PassOut M = finish(im, -0.25, msbm, 0, vm);
    bool which = P.err < M.err;

    float ov[8];
#pragma unroll
    for (int k = 0; k < 8; ++k) {
        double o = which ? (vp[k] - 0.25) : (vm[k] + 0.25);
        ov[k] = (float)o;
    }

    float4* o4 = reinterpret_cast<float4*>(out + (size_t)r * 8);
    o4[0] = make_float4(ov[0], ov[1], ov[2], ov[3]);
    o4[1] = make_float4(ov[4], ov[5], ov[6], ov[7]);
    out[(size_t)N * 8 + r] = (float)(which ? P.idx : M.idx);
}

extern "C" void kernel_launch(void* const* d_in, const int* in_sizes, int n_in,
                              void* d_out, int out_size, void* d_ws, size_t ws_size,
                              hipStream_t stream)
{
    const float* X   = (const float*)d_in[0];
    const float* gp  = (const float*)d_in[1];
    const float* gn  = (const float*)d_in[2];
    const int*   pam = (const int*)d_in[3];
    float* out = (float*)d_out;

    int N = in_sizes[0] / 8;
    int G = in_sizes[1] / 8;
    int blocks = (N + NT - 1) / NT;
    e8p_quant_kernel<<<blocks, NT, 0, stream>>>(X, gp, gn, pam, out, N, G);
}